// Round 3
// baseline (8573.281 us; speedup 1.0000x reference)
//
#include <hip/hip_runtime.h>
#include <math.h>

#define HW 262144
#define C_ 256
#define SAMPLE_NUM_ 4096
#define TAU_ 0.07f
#define RTAU_ (1.0f/0.07f)
#define THRESH_ 0.8f
#define NCHUNK_MAX 41

// ---- ws byte offsets ----
#define OFF_GSUM   0          // double
#define OFF_BSUM   8          // double
#define OFF_CNTS   16         // int[4]: gcnt,bcnt,gcoreCnt,bcoreCnt
#define OFF_MGC    64         // double[2]: mgc, mbc
#define OFF_PLANI  96         // int[16]
#define OFF_CORESUMG 256      // float[256]
#define OFF_CORESUMB 1280     // float[256]
#define OFF_CHUNKSUM 2304     // float[82]
#define OFF_COREMEANG 2688    // float[256]
#define OFF_COREMEANB 3712    // float[256]
#define OFF_NPOS   4736       // float[2]
#define ZERO_BYTES 16384
#define OFF_RNORM  16384                        // float[262144]
#define OFF_CNTPOOL (OFF_RNORM + 262144*4)      // int[4][4096]
#define OFF_OFFPOOL (OFF_CNTPOOL + 4*4096*4)    // int[4][4096]
#define OFF_TOTALS  (OFF_OFFPOOL + 4*4096*4)    // int[4] (+pad)
#define OFF_APIX    (OFF_TOTALS + 64)           // int[8192]
#define OFF_NA      (OFF_APIX + 8192*4)         // float[8192]
#define OFF_PLOG    (OFF_NA + 8192*4)           // float[8192]
#define OFF_RNA     (OFF_PLOG + 8192*4)         // float[8192]
#define OFF_FEATS   (OFF_RNA + 8192*4)          // float[8192*256]

__device__ __forceinline__ float waveReduceSum(float v){
    for(int off=32; off; off>>=1) v += __shfl_down(v, off, 64);
    return v;
}
__device__ __forceinline__ int waveReduceSumI(int v){
    for(int off=32; off; off>>=1) v += __shfl_down(v, off, 64);
    return v;
}

// K1: confidence sums/counts + core counts
__global__ void k_conf(const float* __restrict__ logits, const int* __restrict__ seg, void* ws){
    int tid = blockIdx.x*blockDim.x + threadIdx.x;
    int stride = gridDim.x*blockDim.x;
    float gs=0.f, bs=0.f; int gc=0, bc=0, gcc=0, bcc=0;
    for(int p=tid; p<HW; p+=stride){
        int s = seg[p];
        float l0 = logits[p], l1 = logits[HW+p];
        if(s==1){ gs += l1; gc++; if(l1 >= THRESH_) gcc++; }
        else    { bs += l0; bc++; if(l0 >= THRESH_) bcc++; }
    }
    gs = waveReduceSum(gs); bs = waveReduceSum(bs);
    gc = waveReduceSumI(gc); bc = waveReduceSumI(bc);
    gcc = waveReduceSumI(gcc); bcc = waveReduceSumI(bcc);
    if((threadIdx.x & 63) == 0){
        atomicAdd((double*)((char*)ws+OFF_GSUM), (double)gs);
        atomicAdd((double*)((char*)ws+OFF_BSUM), (double)bs);
        int* c = (int*)((char*)ws+OFF_CNTS);
        atomicAdd(c+0, gc); atomicAdd(c+1, bc);
        atomicAdd(c+2, gcc); atomicAdd(c+3, bcc);
    }
}

// K2: plan part 1
__global__ void k_plan1(void* ws){
    double gs = *(double*)((char*)ws+OFF_GSUM);
    double bs = *(double*)((char*)ws+OFF_BSUM);
    int* cnts = (int*)((char*)ws+OFF_CNTS);
    double mgc = gs / ((double)cnts[0] + 1e-8);
    double mbc = bs / ((double)cnts[1] + 1e-8);
    double* md = (double*)((char*)ws+OFF_MGC);
    md[0]=mgc; md[1]=mbc;
    int* pi = (int*)((char*)ws+OFF_PLANI);
    int eg = (int)(SAMPLE_NUM_*(1.0-mgc)); if(eg<1) eg=1;
    int eb = (int)(SAMPLE_NUM_*(1.0-mbc)); if(eb<1) eb=1;
    pi[0]=eg; pi[1]=SAMPLE_NUM_-eg; pi[2]=eb; pi[3]=SAMPLE_NUM_-eb;
}

// K3 v3: per-pixel reciprocal channel norms; 4096 waves, fully coalesced
__global__ void k_norm(const float* __restrict__ x, void* ws){
    int p = blockIdx.x*blockDim.x + threadIdx.x;   // 262144 threads
    float ss = 0.f;
    #pragma unroll 8
    for(int c=0;c<C_;c++){ float v = x[(size_t)c*HW + p]; ss += v*v; }
    ((float*)((char*)ws+OFF_RNORM))[p] = 1.0f / fmaxf(sqrtf(ss), 1e-12f);
}

// K4: pool counts per 64-pixel thread chunk
__global__ void k_poolcount(const float* __restrict__ logits, const int* __restrict__ seg, void* ws){
    int t = blockIdx.x*blockDim.x + threadIdx.x;  // 4096 threads
    const double* md = (const double*)((char*)ws+OFF_MGC);
    double mgc = md[0], mbc = md[1];
    int cnt[4] = {0,0,0,0};
    int p0 = t*64;
    for(int i=0;i<64;i++){
        int p = p0+i; int s = seg[p]; int q;
        if(s==1) q = ((double)logits[HW+p] >= mgc) ? 0 : 1;
        else     q = ((double)logits[p]    >= mbc) ? 2 : 3;
        cnt[q]++;
    }
    int* cp = (int*)((char*)ws+OFF_CNTPOOL);
    for(int q=0;q<4;q++) cp[q*4096 + t] = cnt[q];
}

// K5: exclusive scan over 4096 thread-chunk counts, one block per pool
__global__ void k_scan(void* ws){
    int q = blockIdx.x, j = threadIdx.x;
    int* cp = (int*)((char*)ws+OFF_CNTPOOL) + q*4096;
    int* op = (int*)((char*)ws+OFF_OFFPOOL) + q*4096;
    __shared__ int s[256];
    int base = j*16, sj=0, loc[16];
    for(int i=0;i<16;i++){ loc[i]=cp[base+i]; sj+=loc[i]; }
    s[j]=sj; __syncthreads();
    for(int off=1; off<256; off<<=1){
        int v = (j>=off)? s[j-off] : 0;
        __syncthreads();
        s[j] += v;
        __syncthreads();
    }
    int ex = s[j]-sj;
    for(int i=0;i<16;i++){ op[base+i]=ex; ex+=loc[i]; }
    if(j==255) ((int*)((char*)ws+OFF_TOTALS))[q] = s[255];
}

// K5b: plan part 2
__global__ void k_plan2(void* ws){
    int* pi = (int*)((char*)ws+OFF_PLANI);
    int* tot = (int*)((char*)ws+OFF_TOTALS);
    int sge = min(tot[0], pi[0]);
    int sgh = min(tot[1], pi[1]);
    int sbe = min(tot[2], pi[2]);
    int sbh = min(tot[3], pi[3]);
    int ng = sge+sgh, nb = sbe+sbh;
    pi[4]=sge; pi[5]=sgh; pi[6]=sbe; pi[7]=sbh;
    pi[8]=ng; pi[9]=nb; pi[10]=ng+nb; pi[11]=nb;
    pi[12]=0; pi[13]=sge; pi[14]=ng; pi[15]=ng+sbe;
}

// K6: deterministic compaction
__global__ void k_fill(const float* __restrict__ logits, const int* __restrict__ seg, void* ws){
    int t = blockIdx.x*blockDim.x + threadIdx.x;
    const double* md = (const double*)((char*)ws+OFF_MGC);
    double mgc = md[0], mbc = md[1];
    int* op = (int*)((char*)ws+OFF_OFFPOOL);
    int* pi = (int*)((char*)ws+OFF_PLANI);
    int* apix = (int*)((char*)ws+OFF_APIX);
    int run[4], sel[4], base[4];
    for(int q=0;q<4;q++){ run[q]=op[q*4096+t]; sel[q]=pi[4+q]; base[q]=pi[12+q]; }
    int p0 = t*64;
    for(int i=0;i<64;i++){
        int p = p0+i; int s = seg[p]; int q;
        if(s==1) q = ((double)logits[HW+p] >= mgc) ? 0 : 1;
        else     q = ((double)logits[p]    >= mbc) ? 2 : 3;
        int r = run[q]++;
        if(r < sel[q]) apix[base[q]+r] = p;
    }
}

// K7: gather + normalize anchor features. grid (128 a-tiles, 16 ch-groups), 256 thr.
__global__ void k_gather(const float* __restrict__ x, void* ws){
    int* pi = (int*)((char*)ws+OFF_PLANI);
    int ntot = pi[10];
    int a0 = blockIdx.x*64;
    int c0 = blockIdx.y*16;
    int tid = threadIdx.x;
    int lane = tid & 63, wid = tid >> 6;
    __shared__ float T[16][65];
    int a = a0 + lane;
    int p = -1; float rn = 0.f;
    if(a < ntot){
        p = ((int*)((char*)ws+OFF_APIX))[a];
        rn = ((float*)((char*)ws+OFF_RNORM))[p];
    }
    #pragma unroll
    for(int i=0;i<4;i++){
        int c = c0 + wid*4 + i;
        float v = (p>=0) ? x[(size_t)c*HW + p]*rn : 0.0f;
        T[wid*4+i][lane] = v;
    }
    __syncthreads();
    int aL = tid & 63, cq = tid >> 6;
    float4 o;
    o.x = T[cq*4+0][aL]; o.y = T[cq*4+1][aL];
    o.z = T[cq*4+2][aL]; o.w = T[cq*4+3][aL];
    *(float4*)&((float*)((char*)ws+OFF_FEATS))[(size_t)(a0+aL)*C_ + c0 + cq*4] = o;
}

// K8: per-channel core sums. 512 blocks x 512 px; wave-per-channel.
__global__ void k_core(const float* __restrict__ x, const float* __restrict__ logits,
                       const int* __restrict__ seg, void* ws){
    __shared__ float wg[512], wb[512];
    int p0 = blockIdx.x*512;
    int tid = threadIdx.x;
    const float* rnorm = (const float*)((char*)ws+OFF_RNORM);
    for(int i=tid; i<512; i+=256){
        int p = p0+i; int s = seg[p];
        float rn = rnorm[p];
        wg[i] = (s==1 && logits[HW+p] >= THRESH_) ? rn : 0.0f;
        wb[i] = (s==0 && logits[p]    >= THRESH_) ? rn : 0.0f;
    }
    __syncthreads();
    float* csg = (float*)((char*)ws+OFF_CORESUMG);
    float* csb = (float*)((char*)ws+OFF_CORESUMB);
    int lane = tid & 63, wid = tid >> 6;
    for(int c=wid; c<C_; c+=4){
        float gs=0.f, bs=0.f;
        #pragma unroll
        for(int i=0;i<8;i++){
            int idx = i*64 + lane;
            float xv = x[(size_t)c*HW + p0 + idx];
            gs += xv*wg[idx]; bs += xv*wb[idx];
        }
        gs = waveReduceSum(gs); bs = waveReduceSum(bs);
        if(lane==0){ atomicAdd(csg+c, gs); atomicAdd(csb+c, bs); }
    }
}

// K9: core means + their norms
__global__ void k_coremean(void* ws){
    int cls = blockIdx.x, c = threadIdx.x;
    int* cnts = (int*)((char*)ws+OFF_CNTS);
    float* sum  = (float*)((char*)ws + (cls? OFF_CORESUMB : OFF_CORESUMG));
    float* mean = (float*)((char*)ws + (cls? OFF_COREMEANB: OFF_COREMEANG));
    int n = cnts[2+cls];
    float m = sum[c]/(float)n;
    mean[c] = m;
    float ss = waveReduceSum(m*m);
    __shared__ float wsum[4];
    int lane = c & 63, wid = c >> 6;
    if(lane==0) wsum[wid]=ss;
    __syncthreads();
    if(c==0) ((float*)((char*)ws+OFF_NPOS))[cls] = sqrtf(wsum[0]+wsum[1]+wsum[2]+wsum[3]);
}

// K10: fused anchor norm + pos logit. One wave per anchor (4 anchors/block).
__global__ void k_anchor(void* ws){
    int* pi = (int*)((char*)ws+OFF_PLANI);
    int ntot = pi[10], ng = pi[8];
    int tid = threadIdx.x;
    int lane = tid & 63, wid = tid >> 6;
    int a = blockIdx.x*4 + wid;
    if(a >= ntot) return;
    int cls = (a < ng) ? 0 : 1;
    const float* mean = (const float*)((char*)ws + (cls? OFF_COREMEANB : OFF_COREMEANG));
    const float* feat = (const float*)((char*)ws+OFF_FEATS) + (size_t)a*C_;
    float4 f = *(const float4*)&feat[lane*4];
    float4 m = *(const float4*)&mean[lane*4];
    float ss = f.x*f.x + f.y*f.y + f.z*f.z + f.w*f.w;
    float dd = f.x*m.x + f.y*m.y + f.z*m.z + f.w*m.w;
    ss = waveReduceSum(ss); dd = waveReduceSum(dd);
    if(lane==0){
        float na = sqrtf(ss);
        float npos = ((float*)((char*)ws+OFF_NPOS))[cls];
        float den = fmaxf(na*npos, 1e-8f);
        ((float*)((char*)ws+OFF_NA))[a]   = na;
        ((float*)((char*)ws+OFF_RNA))[a]  = 1.0f/na;
        ((float*)((char*)ws+OFF_PLOG))[a] = (dd/den)*RTAU_;
    }
}

// K11 v3: fused sim-GEMM + chunk LSE.
// block = 64 anchors x 104 negs, 256 thr (16x16), thread tile 4x7.
// acc = 28 regs; launch_bounds caps VGPR at 128 (no spill).
__global__ __launch_bounds__(256, 4) void k_loss(void* ws){
    int at = blockIdx.x, f = blockIdx.y, l = blockIdx.z;
    int* pi = (int*)((char*)ws+OFF_PLANI);
    int ng = pi[8], nb = pi[9], ntot = pi[10], nbg = pi[11];
    int n_a   = l ? (ntot-nbg) : nbg;
    int n_neg = n_a;
    int nfull = n_neg/100, rem = n_neg%100;
    int nch = nfull + (rem?1:0);
    if(f >= nch) return;
    int cs = (f < nfull) ? 100 : rem;
    int a0 = at*64;
    if(a0 >= n_a) return;
    int abase   = l ? nbg : 0;
    int negbase = l ? nbg : 0;
    const float* feats   = (const float*)((char*)ws+OFF_FEATS);
    const float* rnaArr  = (const float*)((char*)ws+OFF_RNA);
    const float* plogArr = (const float*)((char*)ws+OFF_PLOG);

    __shared__ float A_s[64*36];      // 64 anchors x 32ch (+pad)
    __shared__ float N_s[112*36];     // 104(+8) negs x 32ch (+pad)
    __shared__ float P[16*72];
    __shared__ int   nidx_s[112];
    __shared__ float rnn_s[112];
    __shared__ float rA_s[64];
    int tid = threadIdx.x;
    int arow = tid & 15, ncol = tid >> 4;

    for(int k=tid; k<112; k+=256){
        int fi = -1;
        if(k < cs){
            int i = negbase + f*100 + k;
            fi = (i < nb) ? (ng + i) : (i - nb);
        }
        nidx_s[k] = fi;
        rnn_s[k] = (fi >= 0) ? rnaArr[fi] : 1.0f;
    }
    if(tid < 64) rA_s[tid] = (a0+tid < n_a) ? rnaArr[abase+a0+tid] : 1.0f;

    float acc[4][7];
    #pragma unroll
    for(int i=0;i<4;i++)
        #pragma unroll
        for(int j=0;j<7;j++) acc[i][j]=0.f;

    for(int ct=0; ct<8; ct++){
        __syncthreads();
        {   // A: 512 float4
            int idx = tid;
            #pragma unroll
            for(int it=0; it<2; it++, idx+=256){
                int ar = idx>>3, c4 = idx&7;
                int a = a0 + ar;
                float4 v = {0.f,0.f,0.f,0.f};
                if(a < n_a) v = *(const float4*)&feats[(size_t)(abase+a)*C_ + ct*32 + c4*4];
                *(float4*)&A_s[ar*36 + c4*4] = v;
            }
        }
        {   // N: 896 float4
            int idx = tid;
            #pragma unroll
            for(int it=0; it<4; it++, idx+=256){
                if(idx < 896){
                    int kr = idx>>3, c4 = idx&7;
                    int fi = nidx_s[kr];
                    float4 v = {0.f,0.f,0.f,0.f};
                    if(fi >= 0) v = *(const float4*)&feats[(size_t)fi*C_ + ct*32 + c4*4];
                    *(float4*)&N_s[kr*36 + c4*4] = v;
                }
            }
        }
        __syncthreads();
        #pragma unroll
        for(int c4=0;c4<8;c4++){
            float4 av[4];
            #pragma unroll
            for(int i=0;i<4;i++)
                av[i] = *(const float4*)&A_s[(arow + 16*i)*36 + c4*4];
            #pragma unroll
            for(int j=0;j<7;j++){
                float4 nv = *(const float4*)&N_s[(ncol + 16*j)*36 + c4*4];
                #pragma unroll
                for(int i=0;i<4;i++)
                    acc[i][j] += av[i].x*nv.x + av[i].y*nv.y + av[i].z*nv.z + av[i].w*nv.w;
            }
        }
    }
    // epilogue
    float raT[4], psum[4];
    #pragma unroll
    for(int i=0;i<4;i++){
        raT[i] = rA_s[arow + 16*i] * RTAU_;
        psum[i] = 0.f;
    }
    #pragma unroll
    for(int j=0;j<7;j++){
        int k = ncol + 16*j;
        if(k < cs){
            float rn = rnn_s[k];
            #pragma unroll
            for(int i=0;i<4;i++)
                psum[i] += __expf(acc[i][j] * raT[i] * rn);
        }
    }
    #pragma unroll
    for(int i=0;i<4;i++)
        P[ncol*72 + arow + 16*i] = psum[i];
    __syncthreads();
    if(tid < 64){
        float val = 0.f;
        int a = a0 + tid;
        if(a < n_a){
            float s = 0.f;
            #pragma unroll
            for(int w=0;w<16;w++) s += P[w*72 + tid];
            int ai = abase + a;
            float plog = plogArr[ai];
            val = __logf(s + __expf(plog)) - plog;
        }
        val = waveReduceSum(val);
        if(tid==0)
            atomicAdd((float*)((char*)ws+OFF_CHUNKSUM) + l*NCHUNK_MAX + f, val);
    }
}

// K12: final scalar
__global__ void k_final(void* ws, float* out){
    int* pi = (int*)((char*)ws+OFF_PLANI);
    int ntot = pi[10], nbg = pi[11];
    float* csum = (float*)((char*)ws+OFF_CHUNKSUM);
    float total = 0.f;
    for(int l=0;l<2;l++){
        int n_a = l ? (ntot-nbg) : nbg;
        int n_neg = n_a;
        int nfull = n_neg/100, rem = n_neg%100;
        int nch = nfull + (rem?1:0);
        float s = 0.f;
        for(int f=0; f<nch; f++) s += csum[l*NCHUNK_MAX+f]/(float)n_a;
        total += s/(float)nch;
    }
    *out = total;
}

extern "C" void kernel_launch(void* const* d_in, const int* in_sizes, int n_in,
                              void* d_out, int out_size, void* d_ws, size_t ws_size,
                              hipStream_t stream){
    const float* x      = (const float*)d_in[0];   // (1,256,512,512)
    const float* logits = (const float*)d_in[1];   // (1,2,512,512)
    const int*   seg    = (const int*)d_in[2];     // (1,512,512)
    float* out = (float*)d_out;

    hipMemsetAsync(d_ws, 0, ZERO_BYTES, stream);
    k_conf<<<256,256,0,stream>>>(logits, seg, d_ws);
    k_plan1<<<1,1,0,stream>>>(d_ws);
    k_norm<<<1024,256,0,stream>>>(x, d_ws);
    k_poolcount<<<16,256,0,stream>>>(logits, seg, d_ws);
    k_scan<<<4,256,0,stream>>>(d_ws);
    k_plan2<<<1,1,0,stream>>>(d_ws);
    k_fill<<<16,256,0,stream>>>(logits, seg, d_ws);
    dim3 gg(128, 16);
    k_gather<<<gg,256,0,stream>>>(x, d_ws);
    k_core<<<512,256,0,stream>>>(x, logits, seg, d_ws);
    k_coremean<<<2,256,0,stream>>>(d_ws);
    k_anchor<<<2048,256,0,stream>>>(d_ws);
    dim3 g(64, NCHUNK_MAX, 2);
    k_loss<<<g,256,0,stream>>>(d_ws);
    k_final<<<1,1,0,stream>>>(d_ws, out);
}

// Round 4
// 1738.760 us; speedup vs baseline: 4.9307x; 4.9307x over previous
//
#include <hip/hip_runtime.h>
#include <math.h>

#define HW 262144
#define C_ 256
#define SAMPLE_NUM_ 4096
#define TAU_ 0.07f
#define RTAU_ (1.0f/0.07f)
#define THRESH_ 0.8f
#define NCHUNK_MAX 41

// ---- ws byte offsets ----
#define OFF_GSUM   0          // double
#define OFF_BSUM   8          // double
#define OFF_CNTS   16         // int[4]: gcnt,bcnt,gcoreCnt,bcoreCnt
#define OFF_MGC    64         // double[2]: mgc, mbc
#define OFF_PLANI  96         // int[16]
#define OFF_CORESUMG 256      // float[256]
#define OFF_CORESUMB 1280     // float[256]
#define OFF_CHUNKSUM 2304     // float[82]
#define OFF_COREMEANG 2688    // float[256]
#define OFF_COREMEANB 3712    // float[256]
#define OFF_NPOS   4736       // float[2]
#define ZERO_BYTES 16384
#define OFF_RNORM  16384                        // float[262144]
#define OFF_CNTPOOL (OFF_RNORM + 262144*4)      // int[4][4096]
#define OFF_OFFPOOL (OFF_CNTPOOL + 4*4096*4)    // int[4][4096]
#define OFF_TOTALS  (OFF_OFFPOOL + 4*4096*4)    // int[4] (+pad)
#define OFF_APIX    (OFF_TOTALS + 64)           // int[8192]
#define OFF_NA      (OFF_APIX + 8192*4)         // float[8192]
#define OFF_PLOG    (OFF_NA + 8192*4)           // float[8192]
#define OFF_RNA     (OFF_PLOG + 8192*4)         // float[8192]
#define OFF_FEATS   (OFF_RNA + 8192*4)          // float[8192*256]

__device__ __forceinline__ float waveReduceSum(float v){
    for(int off=32; off; off>>=1) v += __shfl_down(v, off, 64);
    return v;
}
__device__ __forceinline__ int waveReduceSumI(int v){
    for(int off=32; off; off>>=1) v += __shfl_down(v, off, 64);
    return v;
}

// K1: confidence sums/counts + core counts
__global__ void k_conf(const float* __restrict__ logits, const int* __restrict__ seg, void* ws){
    int tid = blockIdx.x*blockDim.x + threadIdx.x;
    int stride = gridDim.x*blockDim.x;
    float gs=0.f, bs=0.f; int gc=0, bc=0, gcc=0, bcc=0;
    for(int p=tid; p<HW; p+=stride){
        int s = seg[p];
        float l0 = logits[p], l1 = logits[HW+p];
        if(s==1){ gs += l1; gc++; if(l1 >= THRESH_) gcc++; }
        else    { bs += l0; bc++; if(l0 >= THRESH_) bcc++; }
    }
    gs = waveReduceSum(gs); bs = waveReduceSum(bs);
    gc = waveReduceSumI(gc); bc = waveReduceSumI(bc);
    gcc = waveReduceSumI(gcc); bcc = waveReduceSumI(bcc);
    if((threadIdx.x & 63) == 0){
        atomicAdd((double*)((char*)ws+OFF_GSUM), (double)gs);
        atomicAdd((double*)((char*)ws+OFF_BSUM), (double)bs);
        int* c = (int*)((char*)ws+OFF_CNTS);
        atomicAdd(c+0, gc); atomicAdd(c+1, bc);
        atomicAdd(c+2, gcc); atomicAdd(c+3, bcc);
    }
}

// K2: plan part 1
__global__ void k_plan1(void* ws){
    double gs = *(double*)((char*)ws+OFF_GSUM);
    double bs = *(double*)((char*)ws+OFF_BSUM);
    int* cnts = (int*)((char*)ws+OFF_CNTS);
    double mgc = gs / ((double)cnts[0] + 1e-8);
    double mbc = bs / ((double)cnts[1] + 1e-8);
    double* md = (double*)((char*)ws+OFF_MGC);
    md[0]=mgc; md[1]=mbc;
    int* pi = (int*)((char*)ws+OFF_PLANI);
    int eg = (int)(SAMPLE_NUM_*(1.0-mgc)); if(eg<1) eg=1;
    int eb = (int)(SAMPLE_NUM_*(1.0-mbc)); if(eb<1) eb=1;
    pi[0]=eg; pi[1]=SAMPLE_NUM_-eg; pi[2]=eb; pi[3]=SAMPLE_NUM_-eb;
}

// K3: per-pixel reciprocal channel norms; 4096 waves, fully coalesced
__global__ void k_norm(const float* __restrict__ x, void* ws){
    int p = blockIdx.x*blockDim.x + threadIdx.x;   // 262144 threads
    float ss = 0.f;
    #pragma unroll 8
    for(int c=0;c<C_;c++){ float v = x[(size_t)c*HW + p]; ss += v*v; }
    ((float*)((char*)ws+OFF_RNORM))[p] = 1.0f / fmaxf(sqrtf(ss), 1e-12f);
}

// K4: pool counts per 64-pixel thread chunk
__global__ void k_poolcount(const float* __restrict__ logits, const int* __restrict__ seg, void* ws){
    int t = blockIdx.x*blockDim.x + threadIdx.x;  // 4096 threads
    const double* md = (const double*)((char*)ws+OFF_MGC);
    double mgc = md[0], mbc = md[1];
    int cnt[4] = {0,0,0,0};
    int p0 = t*64;
    for(int i=0;i<64;i++){
        int p = p0+i; int s = seg[p]; int q;
        if(s==1) q = ((double)logits[HW+p] >= mgc) ? 0 : 1;
        else     q = ((double)logits[p]    >= mbc) ? 2 : 3;
        cnt[q]++;
    }
    int* cp = (int*)((char*)ws+OFF_CNTPOOL);
    for(int q=0;q<4;q++) cp[q*4096 + t] = cnt[q];
}

// K5: exclusive scan over 4096 thread-chunk counts, one block per pool
__global__ void k_scan(void* ws){
    int q = blockIdx.x, j = threadIdx.x;
    int* cp = (int*)((char*)ws+OFF_CNTPOOL) + q*4096;
    int* op = (int*)((char*)ws+OFF_OFFPOOL) + q*4096;
    __shared__ int s[256];
    int base = j*16, sj=0, loc[16];
    for(int i=0;i<16;i++){ loc[i]=cp[base+i]; sj+=loc[i]; }
    s[j]=sj; __syncthreads();
    for(int off=1; off<256; off<<=1){
        int v = (j>=off)? s[j-off] : 0;
        __syncthreads();
        s[j] += v;
        __syncthreads();
    }
    int ex = s[j]-sj;
    for(int i=0;i<16;i++){ op[base+i]=ex; ex+=loc[i]; }
    if(j==255) ((int*)((char*)ws+OFF_TOTALS))[q] = s[255];
}

// K5b: plan part 2
__global__ void k_plan2(void* ws){
    int* pi = (int*)((char*)ws+OFF_PLANI);
    int* tot = (int*)((char*)ws+OFF_TOTALS);
    int sge = min(tot[0], pi[0]);
    int sgh = min(tot[1], pi[1]);
    int sbe = min(tot[2], pi[2]);
    int sbh = min(tot[3], pi[3]);
    int ng = sge+sgh, nb = sbe+sbh;
    pi[4]=sge; pi[5]=sgh; pi[6]=sbe; pi[7]=sbh;
    pi[8]=ng; pi[9]=nb; pi[10]=ng+nb; pi[11]=nb;
    pi[12]=0; pi[13]=sge; pi[14]=ng; pi[15]=ng+sbe;
}

// K6: deterministic compaction
__global__ void k_fill(const float* __restrict__ logits, const int* __restrict__ seg, void* ws){
    int t = blockIdx.x*blockDim.x + threadIdx.x;
    const double* md = (const double*)((char*)ws+OFF_MGC);
    double mgc = md[0], mbc = md[1];
    int* op = (int*)((char*)ws+OFF_OFFPOOL);
    int* pi = (int*)((char*)ws+OFF_PLANI);
    int* apix = (int*)((char*)ws+OFF_APIX);
    int run[4], sel[4], base[4];
    for(int q=0;q<4;q++){ run[q]=op[q*4096+t]; sel[q]=pi[4+q]; base[q]=pi[12+q]; }
    int p0 = t*64;
    for(int i=0;i<64;i++){
        int p = p0+i; int s = seg[p]; int q;
        if(s==1) q = ((double)logits[HW+p] >= mgc) ? 0 : 1;
        else     q = ((double)logits[p]    >= mbc) ? 2 : 3;
        int r = run[q]++;
        if(r < sel[q]) apix[base[q]+r] = p;
    }
}

// K7: gather + normalize anchor features. grid (128 a-tiles, 16 ch-groups), 256 thr.
__global__ void k_gather(const float* __restrict__ x, void* ws){
    int* pi = (int*)((char*)ws+OFF_PLANI);
    int ntot = pi[10];
    int a0 = blockIdx.x*64;
    int c0 = blockIdx.y*16;
    int tid = threadIdx.x;
    int lane = tid & 63, wid = tid >> 6;
    __shared__ float T[16][65];
    int a = a0 + lane;
    int p = -1; float rn = 0.f;
    if(a < ntot){
        p = ((int*)((char*)ws+OFF_APIX))[a];
        rn = ((float*)((char*)ws+OFF_RNORM))[p];
    }
    #pragma unroll
    for(int i=0;i<4;i++){
        int c = c0 + wid*4 + i;
        float v = (p>=0) ? x[(size_t)c*HW + p]*rn : 0.0f;
        T[wid*4+i][lane] = v;
    }
    __syncthreads();
    int aL = tid & 63, cq = tid >> 6;
    float4 o;
    o.x = T[cq*4+0][aL]; o.y = T[cq*4+1][aL];
    o.z = T[cq*4+2][aL]; o.w = T[cq*4+3][aL];
    *(float4*)&((float*)((char*)ws+OFF_FEATS))[(size_t)(a0+aL)*C_ + c0 + cq*4] = o;
}

// K8: per-channel core sums. 512 blocks x 512 px; wave-per-channel.
__global__ void k_core(const float* __restrict__ x, const float* __restrict__ logits,
                       const int* __restrict__ seg, void* ws){
    __shared__ float wg[512], wb[512];
    int p0 = blockIdx.x*512;
    int tid = threadIdx.x;
    const float* rnorm = (const float*)((char*)ws+OFF_RNORM);
    for(int i=tid; i<512; i+=256){
        int p = p0+i; int s = seg[p];
        float rn = rnorm[p];
        wg[i] = (s==1 && logits[HW+p] >= THRESH_) ? rn : 0.0f;
        wb[i] = (s==0 && logits[p]    >= THRESH_) ? rn : 0.0f;
    }
    __syncthreads();
    float* csg = (float*)((char*)ws+OFF_CORESUMG);
    float* csb = (float*)((char*)ws+OFF_CORESUMB);
    int lane = tid & 63, wid = tid >> 6;
    for(int c=wid; c<C_; c+=4){
        float gs=0.f, bs=0.f;
        #pragma unroll
        for(int i=0;i<8;i++){
            int idx = i*64 + lane;
            float xv = x[(size_t)c*HW + p0 + idx];
            gs += xv*wg[idx]; bs += xv*wb[idx];
        }
        gs = waveReduceSum(gs); bs = waveReduceSum(bs);
        if(lane==0){ atomicAdd(csg+c, gs); atomicAdd(csb+c, bs); }
    }
}

// K9: core means + their norms
__global__ void k_coremean(void* ws){
    int cls = blockIdx.x, c = threadIdx.x;
    int* cnts = (int*)((char*)ws+OFF_CNTS);
    float* sum  = (float*)((char*)ws + (cls? OFF_CORESUMB : OFF_CORESUMG));
    float* mean = (float*)((char*)ws + (cls? OFF_COREMEANB: OFF_COREMEANG));
    int n = cnts[2+cls];
    float m = sum[c]/(float)n;
    mean[c] = m;
    float ss = waveReduceSum(m*m);
    __shared__ float wsum[4];
    int lane = c & 63, wid = c >> 6;
    if(lane==0) wsum[wid]=ss;
    __syncthreads();
    if(c==0) ((float*)((char*)ws+OFF_NPOS))[cls] = sqrtf(wsum[0]+wsum[1]+wsum[2]+wsum[3]);
}

// K10: fused anchor norm + pos logit. One wave per anchor (4 anchors/block).
__global__ void k_anchor(void* ws){
    int* pi = (int*)((char*)ws+OFF_PLANI);
    int ntot = pi[10], ng = pi[8];
    int tid = threadIdx.x;
    int lane = tid & 63, wid = tid >> 6;
    int a = blockIdx.x*4 + wid;
    if(a >= ntot) return;
    int cls = (a < ng) ? 0 : 1;
    const float* mean = (const float*)((char*)ws + (cls? OFF_COREMEANB : OFF_COREMEANG));
    const float* feat = (const float*)((char*)ws+OFF_FEATS) + (size_t)a*C_;
    float4 f = *(const float4*)&feat[lane*4];
    float4 m = *(const float4*)&mean[lane*4];
    float ss = f.x*f.x + f.y*f.y + f.z*f.z + f.w*f.w;
    float dd = f.x*m.x + f.y*m.y + f.z*m.z + f.w*m.w;
    ss = waveReduceSum(ss); dd = waveReduceSum(dd);
    if(lane==0){
        float na = sqrtf(ss);
        float npos = ((float*)((char*)ws+OFF_NPOS))[cls];
        float den = fmaxf(na*npos, 1e-8f);
        ((float*)((char*)ws+OFF_NA))[a]   = na;
        ((float*)((char*)ws+OFF_RNA))[a]  = 1.0f/na;
        ((float*)((char*)ws+OFF_PLOG))[a] = (dd/den)*RTAU_;
    }
}

// K11 v4: fused sim-GEMM + chunk LSE.
// block = 64 anchors x 104 negs, 256 thr. Thread: a=tid>>3 (2 anchors: a, a+32),
// j=tid&7 (13 negs stride 8). float4 LDS reads, stride-36 rows:
//   A rows = lane>>3 -> 8 distinct rows/wave on distinct bank quads (broadcast x8)
//   N rows = lane&7 + 8j -> stride-1 rows on distinct bank quads (broadcast x8)
// => conflict-free b128 reads. acc = 26 regs (round-1-proven footprint). No
// min-occupancy hint (launch_bounds(256,4) caused catastrophic spill in R3).
__global__ __launch_bounds__(256) void k_loss(void* ws){
    int at = blockIdx.x, f = blockIdx.y, l = blockIdx.z;
    int* pi = (int*)((char*)ws+OFF_PLANI);
    int ng = pi[8], nb = pi[9], ntot = pi[10], nbg = pi[11];
    int n_a   = l ? (ntot-nbg) : nbg;
    int n_neg = n_a;
    int nfull = n_neg/100, rem = n_neg%100;
    int nch = nfull + (rem?1:0);
    if(f >= nch) return;
    int cs = (f < nfull) ? 100 : rem;
    int a0 = at*64;
    if(a0 >= n_a) return;
    int abase   = l ? nbg : 0;
    int negbase = l ? nbg : 0;
    const float* feats   = (const float*)((char*)ws+OFF_FEATS);
    const float* rnaArr  = (const float*)((char*)ws+OFF_RNA);
    const float* plogArr = (const float*)((char*)ws+OFF_PLOG);

    __shared__ float A_s[64*36];
    __shared__ float N_s[104*36];
    __shared__ float P[8*68];
    __shared__ int   nidx_s[104];
    __shared__ float rnn_s[104];
    __shared__ float rA_s[64];
    int tid = threadIdx.x;
    int aT = tid >> 3;     // 0..31
    int jT = tid & 7;      // 0..7

    for(int k=tid; k<104; k+=256){
        int fi = -1;
        if(k < cs){
            int i = negbase + f*100 + k;
            fi = (i < nb) ? (ng + i) : (i - nb);
        }
        nidx_s[k] = fi;
        rnn_s[k] = (fi >= 0) ? rnaArr[fi] : 1.0f;
    }
    if(tid < 64) rA_s[tid] = (a0+tid < n_a) ? rnaArr[abase+a0+tid] : 1.0f;

    float acc0[13], acc1[13];
    #pragma unroll
    for(int j=0;j<13;j++){ acc0[j]=0.f; acc1[j]=0.f; }

    for(int ct=0; ct<8; ct++){
        __syncthreads();
        {   // stage A: 512 float4
            int idx = tid;
            #pragma unroll
            for(int it=0; it<2; it++, idx+=256){
                int ar = idx>>3, c4 = idx&7;
                int a = a0 + ar;
                float4 v = {0.f,0.f,0.f,0.f};
                if(a < n_a) v = *(const float4*)&feats[(size_t)(abase+a)*C_ + ct*32 + c4*4];
                *(float4*)&A_s[ar*36 + c4*4] = v;
            }
        }
        {   // stage N: 832 float4
            int idx = tid;
            #pragma unroll
            for(int it=0; it<4; it++, idx+=256){
                if(idx < 832){
                    int kr = idx>>3, c4 = idx&7;
                    int fi = nidx_s[kr];
                    float4 v = {0.f,0.f,0.f,0.f};
                    if(fi >= 0) v = *(const float4*)&feats[(size_t)fi*C_ + ct*32 + c4*4];
                    *(float4*)&N_s[kr*36 + c4*4] = v;
                }
            }
        }
        __syncthreads();
        #pragma unroll
        for(int c4=0;c4<8;c4++){
            float4 av0 = *(const float4*)&A_s[aT*36 + c4*4];
            float4 av1 = *(const float4*)&A_s[(aT+32)*36 + c4*4];
            #pragma unroll
            for(int j=0;j<13;j++){
                float4 nv = *(const float4*)&N_s[(jT + 8*j)*36 + c4*4];
                acc0[j] += av0.x*nv.x + av0.y*nv.y + av0.z*nv.z + av0.w*nv.w;
                acc1[j] += av1.x*nv.x + av1.y*nv.y + av1.z*nv.z + av1.w*nv.w;
            }
        }
    }
    // epilogue: per-thread partial exp-sums over its 13 negs
    float ra0 = rA_s[aT]    * RTAU_;
    float ra1 = rA_s[aT+32] * RTAU_;
    float ps0 = 0.f, ps1 = 0.f;
    #pragma unroll
    for(int j=0;j<13;j++){
        int k = jT + 8*j;
        if(k < cs){
            float rn = rnn_s[k];
            ps0 += __expf(acc0[j] * ra0 * rn);
            ps1 += __expf(acc1[j] * ra1 * rn);
        }
    }
    P[jT*68 + aT]      = ps0;
    P[jT*68 + aT + 32] = ps1;
    __syncthreads();
    if(tid < 64){
        float val = 0.f;
        int a = a0 + tid;
        if(a < n_a){
            float s = 0.f;
            #pragma unroll
            for(int w=0;w<8;w++) s += P[w*68 + tid];
            int ai = abase + a;
            float plog = plogArr[ai];
            val = __logf(s + __expf(plog)) - plog;
        }
        val = waveReduceSum(val);
        if(tid==0)
            atomicAdd((float*)((char*)ws+OFF_CHUNKSUM) + l*NCHUNK_MAX + f, val);
    }
}

// K12: final scalar
__global__ void k_final(void* ws, float* out){
    int* pi = (int*)((char*)ws+OFF_PLANI);
    int ntot = pi[10], nbg = pi[11];
    float* csum = (float*)((char*)ws+OFF_CHUNKSUM);
    float total = 0.f;
    for(int l=0;l<2;l++){
        int n_a = l ? (ntot-nbg) : nbg;
        int n_neg = n_a;
        int nfull = n_neg/100, rem = n_neg%100;
        int nch = nfull + (rem?1:0);
        float s = 0.f;
        for(int f=0; f<nch; f++) s += csum[l*NCHUNK_MAX+f]/(float)n_a;
        total += s/(float)nch;
    }
    *out = total;
}

extern "C" void kernel_launch(void* const* d_in, const int* in_sizes, int n_in,
                              void* d_out, int out_size, void* d_ws, size_t ws_size,
                              hipStream_t stream){
    const float* x      = (const float*)d_in[0];   // (1,256,512,512)
    const float* logits = (const float*)d_in[1];   // (1,2,512,512)
    const int*   seg    = (const int*)d_in[2];     // (1,512,512)
    float* out = (float*)d_out;

    hipMemsetAsync(d_ws, 0, ZERO_BYTES, stream);
    k_conf<<<256,256,0,stream>>>(logits, seg, d_ws);
    k_plan1<<<1,1,0,stream>>>(d_ws);
    k_norm<<<1024,256,0,stream>>>(x, d_ws);
    k_poolcount<<<16,256,0,stream>>>(logits, seg, d_ws);
    k_scan<<<4,256,0,stream>>>(d_ws);
    k_plan2<<<1,1,0,stream>>>(d_ws);
    k_fill<<<16,256,0,stream>>>(logits, seg, d_ws);
    dim3 gg(128, 16);
    k_gather<<<gg,256,0,stream>>>(x, d_ws);
    k_core<<<512,256,0,stream>>>(x, logits, seg, d_ws);
    k_coremean<<<2,256,0,stream>>>(d_ws);
    k_anchor<<<2048,256,0,stream>>>(d_ws);
    dim3 g(64, NCHUNK_MAX, 2);
    k_loss<<<g,256,0,stream>>>(d_ws);
    k_final<<<1,1,0,stream>>>(d_ws, out);
}

// Round 5
// 732.181 us; speedup vs baseline: 11.7092x; 2.3748x over previous
//
#include <hip/hip_runtime.h>
#include <math.h>

#define HW 262144
#define C_ 256
#define SAMPLE_NUM_ 4096
#define TAU_ 0.07f
#define RTAU_ (1.0f/0.07f)
#define THRESH_ 0.8f
#define NCHUNK_MAX 41
#define NPB 512              // k_core partial blocks

typedef _Float16 half_t;
typedef __attribute__((ext_vector_type(4))) _Float16 half4;
typedef __attribute__((ext_vector_type(8))) _Float16 half8;
typedef __attribute__((ext_vector_type(4))) float f32x4;

// ---- ws byte offsets ----
#define OFF_GSUM   0          // double
#define OFF_BSUM   8          // double
#define OFF_CNTS   16         // int[4]: gcnt,bcnt,gcoreCnt,bcoreCnt
#define OFF_MGC    64         // double[2]: mgc, mbc
#define OFF_PLANI  96         // int[16]
#define OFF_CORESUMG 256      // float[256]
#define OFF_CORESUMB 1280     // float[256] (contiguous after CORESUMG)
#define OFF_CHUNKSUM 2304     // float[82]
#define OFF_COREMEANG 2688    // float[256]
#define OFF_COREMEANB 3712    // float[256]
#define OFF_NPOS   4736       // float[2]
#define ZERO_BYTES 16384
#define OFF_RNORM  16384                        // float[262144]
#define OFF_CNTPOOL (OFF_RNORM + 262144*4)      // int[4][4096]
#define OFF_OFFPOOL (OFF_CNTPOOL + 4*4096*4)    // int[4][4096]
#define OFF_TOTALS  (OFF_OFFPOOL + 4*4096*4)    // int[4] (+pad)
#define OFF_APIX    (OFF_TOTALS + 64)           // int[8192]
#define OFF_NA      (OFF_APIX + 8192*4)         // float[8192]
#define OFF_PLOG    (OFF_NA + 8192*4)           // float[8192]
#define OFF_RNA     (OFF_PLOG + 8192*4)         // float[8192]
#define OFF_FEATSH  (OFF_RNA + 8192*4)          // half[8192*256]  (4 MB, 16B-aligned)
#define OFF_PART    (OFF_FEATSH + 8192*256*2)   // float[512][NPB] (1 MB)

__device__ __forceinline__ float waveReduceSum(float v){
    for(int off=32; off; off>>=1) v += __shfl_down(v, off, 64);
    return v;
}
__device__ __forceinline__ int waveReduceSumI(int v){
    for(int off=32; off; off>>=1) v += __shfl_down(v, off, 64);
    return v;
}

// K1: confidence sums/counts + core counts (block-reduced, 1 atomic set per block)
__global__ void k_conf(const float* __restrict__ logits, const int* __restrict__ seg, void* ws){
    int tid = blockIdx.x*blockDim.x + threadIdx.x;
    int stride = gridDim.x*blockDim.x;
    float gs=0.f, bs=0.f; int gc=0, bc=0, gcc=0, bcc=0;
    for(int p=tid; p<HW; p+=stride){
        int s = seg[p];
        float l0 = logits[p], l1 = logits[HW+p];
        if(s==1){ gs += l1; gc++; if(l1 >= THRESH_) gcc++; }
        else    { bs += l0; bc++; if(l0 >= THRESH_) bcc++; }
    }
    gs = waveReduceSum(gs); bs = waveReduceSum(bs);
    gc = waveReduceSumI(gc); bc = waveReduceSumI(bc);
    gcc = waveReduceSumI(gcc); bcc = waveReduceSumI(bcc);
    __shared__ float rf[8];
    __shared__ int   ri[16];
    int lane = threadIdx.x & 63, wid = threadIdx.x >> 6;
    if(lane==0){
        rf[wid]=gs; rf[4+wid]=bs;
        ri[wid]=gc; ri[4+wid]=bc; ri[8+wid]=gcc; ri[12+wid]=bcc;
    }
    __syncthreads();
    if(threadIdx.x==0){
        float G=rf[0]+rf[1]+rf[2]+rf[3], B=rf[4]+rf[5]+rf[6]+rf[7];
        int GC=ri[0]+ri[1]+ri[2]+ri[3], BC=ri[4]+ri[5]+ri[6]+ri[7];
        int GCC=ri[8]+ri[9]+ri[10]+ri[11], BCC=ri[12]+ri[13]+ri[14]+ri[15];
        atomicAdd((double*)((char*)ws+OFF_GSUM), (double)G);
        atomicAdd((double*)((char*)ws+OFF_BSUM), (double)B);
        int* c = (int*)((char*)ws+OFF_CNTS);
        atomicAdd(c+0, GC); atomicAdd(c+1, BC);
        atomicAdd(c+2, GCC); atomicAdd(c+3, BCC);
    }
}

// K2: plan part 1
__global__ void k_plan1(void* ws){
    double gs = *(double*)((char*)ws+OFF_GSUM);
    double bs = *(double*)((char*)ws+OFF_BSUM);
    int* cnts = (int*)((char*)ws+OFF_CNTS);
    double mgc = gs / ((double)cnts[0] + 1e-8);
    double mbc = bs / ((double)cnts[1] + 1e-8);
    double* md = (double*)((char*)ws+OFF_MGC);
    md[0]=mgc; md[1]=mbc;
    int* pi = (int*)((char*)ws+OFF_PLANI);
    int eg = (int)(SAMPLE_NUM_*(1.0-mgc)); if(eg<1) eg=1;
    int eb = (int)(SAMPLE_NUM_*(1.0-mbc)); if(eb<1) eb=1;
    pi[0]=eg; pi[1]=SAMPLE_NUM_-eg; pi[2]=eb; pi[3]=SAMPLE_NUM_-eb;
}

// K3: per-pixel reciprocal channel norms; fully coalesced
__global__ void k_norm(const float* __restrict__ x, void* ws){
    int p = blockIdx.x*blockDim.x + threadIdx.x;
    float ss = 0.f;
    #pragma unroll 8
    for(int c=0;c<C_;c++){ float v = x[(size_t)c*HW + p]; ss += v*v; }
    ((float*)((char*)ws+OFF_RNORM))[p] = 1.0f / fmaxf(sqrtf(ss), 1e-12f);
}

// K4: pool counts per 64-pixel thread chunk
__global__ void k_poolcount(const float* __restrict__ logits, const int* __restrict__ seg, void* ws){
    int t = blockIdx.x*blockDim.x + threadIdx.x;  // 4096 threads
    const double* md = (const double*)((char*)ws+OFF_MGC);
    double mgc = md[0], mbc = md[1];
    int cnt[4] = {0,0,0,0};
    int p0 = t*64;
    for(int i=0;i<64;i++){
        int p = p0+i; int s = seg[p]; int q;
        if(s==1) q = ((double)logits[HW+p] >= mgc) ? 0 : 1;
        else     q = ((double)logits[p]    >= mbc) ? 2 : 3;
        cnt[q]++;
    }
    int* cp = (int*)((char*)ws+OFF_CNTPOOL);
    for(int q=0;q<4;q++) cp[q*4096 + t] = cnt[q];
}

// K5: exclusive scan over 4096 thread-chunk counts, one block per pool
__global__ void k_scan(void* ws){
    int q = blockIdx.x, j = threadIdx.x;
    int* cp = (int*)((char*)ws+OFF_CNTPOOL) + q*4096;
    int* op = (int*)((char*)ws+OFF_OFFPOOL) + q*4096;
    __shared__ int s[256];
    int base = j*16, sj=0, loc[16];
    for(int i=0;i<16;i++){ loc[i]=cp[base+i]; sj+=loc[i]; }
    s[j]=sj; __syncthreads();
    for(int off=1; off<256; off<<=1){
        int v = (j>=off)? s[j-off] : 0;
        __syncthreads();
        s[j] += v;
        __syncthreads();
    }
    int ex = s[j]-sj;
    for(int i=0;i<16;i++){ op[base+i]=ex; ex+=loc[i]; }
    if(j==255) ((int*)((char*)ws+OFF_TOTALS))[q] = s[255];
}

// K5b: plan part 2
__global__ void k_plan2(void* ws){
    int* pi = (int*)((char*)ws+OFF_PLANI);
    int* tot = (int*)((char*)ws+OFF_TOTALS);
    int sge = min(tot[0], pi[0]);
    int sgh = min(tot[1], pi[1]);
    int sbe = min(tot[2], pi[2]);
    int sbh = min(tot[3], pi[3]);
    int ng = sge+sgh, nb = sbe+sbh;
    pi[4]=sge; pi[5]=sgh; pi[6]=sbe; pi[7]=sbh;
    pi[8]=ng; pi[9]=nb; pi[10]=ng+nb; pi[11]=nb;
    pi[12]=0; pi[13]=sge; pi[14]=ng; pi[15]=ng+sbe;
}

// K6: deterministic compaction
__global__ void k_fill(const float* __restrict__ logits, const int* __restrict__ seg, void* ws){
    int t = blockIdx.x*blockDim.x + threadIdx.x;
    const double* md = (const double*)((char*)ws+OFF_MGC);
    double mgc = md[0], mbc = md[1];
    int* op = (int*)((char*)ws+OFF_OFFPOOL);
    int* pi = (int*)((char*)ws+OFF_PLANI);
    int* apix = (int*)((char*)ws+OFF_APIX);
    int run[4], sel[4], base[4];
    for(int q=0;q<4;q++){ run[q]=op[q*4096+t]; sel[q]=pi[4+q]; base[q]=pi[12+q]; }
    int p0 = t*64;
    for(int i=0;i<64;i++){
        int p = p0+i; int s = seg[p]; int q;
        if(s==1) q = ((double)logits[HW+p] >= mgc) ? 0 : 1;
        else     q = ((double)logits[p]    >= mbc) ? 2 : 3;
        int r = run[q]++;
        if(r < sel[q]) apix[base[q]+r] = p;
    }
}

// K7: gather + normalize anchor features -> fp16 table. grid (128 a-tiles, 16 ch-groups).
__global__ void k_gather(const float* __restrict__ x, void* ws){
    int* pi = (int*)((char*)ws+OFF_PLANI);
    int ntot = pi[10];
    int a0 = blockIdx.x*64;
    int c0 = blockIdx.y*16;
    int tid = threadIdx.x;
    int lane = tid & 63, wid = tid >> 6;
    __shared__ float T[16][65];
    int a = a0 + lane;
    int p = -1; float rn = 0.f;
    if(a < ntot){
        p = ((int*)((char*)ws+OFF_APIX))[a];
        rn = ((float*)((char*)ws+OFF_RNORM))[p];
    }
    #pragma unroll
    for(int i=0;i<4;i++){
        int c = c0 + wid*4 + i;
        float v = (p>=0) ? x[(size_t)c*HW + p]*rn : 0.0f;
        T[wid*4+i][lane] = v;
    }
    __syncthreads();
    int aL = tid & 63, cq = tid >> 6;
    half4 h;
    h[0] = (half_t)T[cq*4+0][aL]; h[1] = (half_t)T[cq*4+1][aL];
    h[2] = (half_t)T[cq*4+2][aL]; h[3] = (half_t)T[cq*4+3][aL];
    *(half4*)&((half_t*)((char*)ws+OFF_FEATSH))[(size_t)(a0+aL)*C_ + c0 + cq*4] = h;
}

// K8a: per-channel core sums -> per-block partials (no contended atomics)
__global__ void k_core(const float* __restrict__ x, const float* __restrict__ logits,
                       const int* __restrict__ seg, void* ws){
    __shared__ float wg[512], wb[512];
    int p0 = blockIdx.x*512;
    int tid = threadIdx.x;
    const float* rnorm = (const float*)((char*)ws+OFF_RNORM);
    for(int i=tid; i<512; i+=256){
        int p = p0+i; int s = seg[p];
        float rn = rnorm[p];
        wg[i] = (s==1 && logits[HW+p] >= THRESH_) ? rn : 0.0f;
        wb[i] = (s==0 && logits[p]    >= THRESH_) ? rn : 0.0f;
    }
    __syncthreads();
    float* part = (float*)((char*)ws+OFF_PART);
    int lane = tid & 63, wid = tid >> 6;
    for(int c=wid; c<C_; c+=4){
        float gs=0.f, bs=0.f;
        #pragma unroll
        for(int i=0;i<8;i++){
            int idx = i*64 + lane;
            float xv = x[(size_t)c*HW + p0 + idx];
            gs += xv*wg[idx]; bs += xv*wb[idx];
        }
        gs = waveReduceSum(gs); bs = waveReduceSum(bs);
        if(lane==0){
            part[(size_t)c*NPB + blockIdx.x]       = gs;
            part[(size_t)(256+c)*NPB + blockIdx.x] = bs;
        }
    }
}

// K8b: reduce partials -> core sums. 8 blocks x 256 thr = 32 waves; 512 (cls,c) pairs.
__global__ void k_cored(void* ws){
    const float* part = (const float*)((char*)ws+OFF_PART);
    float* csum = (float*)((char*)ws+OFF_CORESUMG);   // [512] contiguous (G then B)
    int gw = (blockIdx.x*256 + threadIdx.x) >> 6;
    int lane = threadIdx.x & 63;
    for(int pair = gw; pair < 512; pair += 32){
        float s = 0.f;
        for(int i=lane; i<NPB; i+=64) s += part[(size_t)pair*NPB + i];
        s = waveReduceSum(s);
        if(lane==0) csum[pair] = s;
    }
}

// K9: core means + their norms
__global__ void k_coremean(void* ws){
    int cls = blockIdx.x, c = threadIdx.x;
    int* cnts = (int*)((char*)ws+OFF_CNTS);
    float* sum  = (float*)((char*)ws + (cls? OFF_CORESUMB : OFF_CORESUMG));
    float* mean = (float*)((char*)ws + (cls? OFF_COREMEANB: OFF_COREMEANG));
    int n = cnts[2+cls];
    float m = sum[c]/(float)n;
    mean[c] = m;
    float ss = waveReduceSum(m*m);
    __shared__ float wsum[4];
    int lane = c & 63, wid = c >> 6;
    if(lane==0) wsum[wid]=ss;
    __syncthreads();
    if(c==0) ((float*)((char*)ws+OFF_NPOS))[cls] = sqrtf(wsum[0]+wsum[1]+wsum[2]+wsum[3]);
}

// K10: fused anchor norm + pos logit from fp16 feats. One wave per anchor.
__global__ void k_anchor(void* ws){
    int* pi = (int*)((char*)ws+OFF_PLANI);
    int ntot = pi[10], ng = pi[8];
    int tid = threadIdx.x;
    int lane = tid & 63, wid = tid >> 6;
    int a = blockIdx.x*4 + wid;
    if(a >= ntot) return;
    int cls = (a < ng) ? 0 : 1;
    const float* mean = (const float*)((char*)ws + (cls? OFF_COREMEANB : OFF_COREMEANG));
    const half_t* feat = (const half_t*)((char*)ws+OFF_FEATSH) + (size_t)a*C_;
    half4 f4 = *(const half4*)&feat[lane*4];
    float fx = (float)f4[0], fy = (float)f4[1], fz = (float)f4[2], fw = (float)f4[3];
    float4 m = *(const float4*)&mean[lane*4];
    float ss = fx*fx + fy*fy + fz*fz + fw*fw;
    float dd = fx*m.x + fy*m.y + fz*m.z + fw*m.w;
    ss = waveReduceSum(ss); dd = waveReduceSum(dd);
    if(lane==0){
        float na = sqrtf(ss);
        float npos = ((float*)((char*)ws+OFF_NPOS))[cls];
        float den = fmaxf(na*npos, 1e-8f);
        ((float*)((char*)ws+OFF_NA))[a]   = na;
        ((float*)((char*)ws+OFF_RNA))[a]  = 1.0f/na;
        ((float*)((char*)ws+OFF_PLOG))[a] = (dd/den)*RTAU_;
    }
}

// K11 v5: MFMA sim-GEMM + chunk LSE. fp16 feats read directly from L2/L3-cached
// global (no LDS, no barriers). Block = 4 independent waves; wave tile = 32
// anchors (2 MFMA rows) x 112 negs (7 MFMA cols), K = 256 in 8 steps of 32.
// A/B frag: lane reads row (lane&15), 8 ch at (lane>>4)*8 — 16B loads.
// C/D: n = lane&15, m = (lane>>4)*4 + reg (verified layout).
__global__ __launch_bounds__(256) void k_loss(void* ws){
    int at = blockIdx.x, f = blockIdx.y, l = blockIdx.z;
    int* pi = (int*)((char*)ws+OFF_PLANI);
    int ng = pi[8], nb = pi[9], ntot = pi[10], nbg = pi[11];
    int n_a = l ? (ntot-nbg) : nbg;
    int nfull = n_a/100, rem = n_a%100;
    int nch = nfull + (rem?1:0);
    if(f >= nch) return;
    int cs = (f < nfull) ? 100 : rem;
    int a0b = at*128;
    if(a0b >= n_a) return;
    int abase   = l ? nbg : 0;
    int negbase = l ? nbg : 0;
    const half_t* fh     = (const half_t*)((char*)ws+OFF_FEATSH);
    const float* rnaArr  = (const float*)((char*)ws+OFF_RNA);
    const float* plogArr = (const float*)((char*)ws+OFF_PLOG);

    int tid = threadIdx.x;
    int wv = tid >> 6, lane = tid & 63;
    int qd = lane >> 4, ln = lane & 15;
    int a0 = a0b + wv*32;

    // 7 neg tiles: this lane's B-row per tile + its rnn
    const half_t* pn[7]; float rnn[7];
    #pragma unroll
    for(int t=0;t<7;t++){
        int k = 16*t + ln;
        int fi = 0; float rn = 1.0f;
        if(k < cs){
            int i = negbase + f*100 + k;
            fi = (i < nb) ? (ng + i) : (i - nb);
            rn = rnaArr[fi];
        }
        pn[t] = fh + (size_t)fi*C_ + qd*8;
        rnn[t] = rn;
    }
    const half_t* pa0 = fh + (size_t)(abase + a0 + ln)*C_ + qd*8;
    const half_t* pa1 = pa0 + 16*C_;

    f32x4 acc[2][7];
    #pragma unroll
    for(int i=0;i<2;i++)
        #pragma unroll
        for(int t=0;t<7;t++) acc[i][t] = (f32x4){0.f,0.f,0.f,0.f};

    #pragma unroll 1
    for(int ks=0; ks<8; ks++){
        half8 af0 = *(const half8*)(pa0 + ks*32);
        half8 af1 = *(const half8*)(pa1 + ks*32);
        #pragma unroll
        for(int t=0;t<7;t++){
            half8 bf = *(const half8*)(pn[t] + ks*32);
            acc[0][t] = __builtin_amdgcn_mfma_f32_16x16x32_f16(af0, bf, acc[0][t], 0,0,0);
            acc[1][t] = __builtin_amdgcn_mfma_f32_16x16x32_f16(af1, bf, acc[1][t], 0,0,0);
        }
    }

    // epilogue: per-lane exp-sums over its 7 n-cols, 16-lane quad reduce
    float myval = 0.f;
    #pragma unroll
    for(int ta=0; ta<2; ta++){
        #pragma unroll
        for(int r=0;r<4;r++){
            int a = a0 + 16*ta + 4*qd + r;
            float ra = (a < n_a) ? rnaArr[abase+a]*RTAU_ : 0.f;
            float s = 0.f;
            #pragma unroll
            for(int tn=0;tn<7;tn++){
                if(16*tn + ln < cs)
                    s += __expf(acc[ta][tn][r] * ra * rnn[tn]);
            }
            if(a >= n_a) s = 0.f;
            #pragma unroll
            for(int off=8; off; off>>=1) s += __shfl_down(s, off, 64);
            if(ln == 0 && a < n_a){
                float plog = plogArr[abase+a];
                myval += __logf(s + __expf(plog)) - plog;
            }
        }
    }
    myval = waveReduceSum(myval);
    if(lane==0)
        atomicAdd((float*)((char*)ws+OFF_CHUNKSUM) + l*NCHUNK_MAX + f, myval);
}

// K12: final scalar
__global__ void k_final(void* ws, float* out){
    int* pi = (int*)((char*)ws+OFF_PLANI);
    int ntot = pi[10], nbg = pi[11];
    float* csum = (float*)((char*)ws+OFF_CHUNKSUM);
    float total = 0.f;
    for(int l=0;l<2;l++){
        int n_a = l ? (ntot-nbg) : nbg;
        int nfull = n_a/100, rem = n_a%100;
        int nch = nfull + (rem?1:0);
        float s = 0.f;
        for(int f=0; f<nch; f++) s += csum[l*NCHUNK_MAX+f]/(float)n_a;
        total += s/(float)nch;
    }
    *out = total;
}

extern "C" void kernel_launch(void* const* d_in, const int* in_sizes, int n_in,
                              void* d_out, int out_size, void* d_ws, size_t ws_size,
                              hipStream_t stream){
    const float* x      = (const float*)d_in[0];   // (1,256,512,512)
    const float* logits = (const float*)d_in[1];   // (1,2,512,512)
    const int*   seg    = (const int*)d_in[2];     // (1,512,512)
    float* out = (float*)d_out;

    hipMemsetAsync(d_ws, 0, ZERO_BYTES, stream);
    k_conf<<<256,256,0,stream>>>(logits, seg, d_ws);
    k_plan1<<<1,1,0,stream>>>(d_ws);
    k_norm<<<1024,256,0,stream>>>(x, d_ws);
    k_poolcount<<<16,256,0,stream>>>(logits, seg, d_ws);
    k_scan<<<4,256,0,stream>>>(d_ws);
    k_plan2<<<1,1,0,stream>>>(d_ws);
    k_fill<<<16,256,0,stream>>>(logits, seg, d_ws);
    dim3 gg(128, 16);
    k_gather<<<gg,256,0,stream>>>(x, d_ws);
    k_core<<<NPB,256,0,stream>>>(x, logits, seg, d_ws);
    k_cored<<<8,256,0,stream>>>(d_ws);
    k_coremean<<<2,256,0,stream>>>(d_ws);
    k_anchor<<<2048,256,0,stream>>>(d_ws);
    dim3 g(32, NCHUNK_MAX, 2);
    k_loss<<<g,256,0,stream>>>(d_ws);
    k_final<<<1,1,0,stream>>>(d_ws, out);
}